// Round 6
// baseline (455.728 us; speedup 1.0000x reference)
//
#include <hip/hip_runtime.h>
#include <hip/hip_bf16.h>
#include <stdint.h>

#define DI __device__ __forceinline__

typedef __bf16 bf16x8 __attribute__((ext_vector_type(8)));
typedef __bf16 bf16x4 __attribute__((ext_vector_type(4)));
typedef float  f32x4  __attribute__((ext_vector_type(4)));

constexpr int Bc = 2, Sc = 2048, Dm = 1024, Hc = 16;
constexpr int Mrows = Bc * Sc;          // 4096
constexpr float LOG2E = 1.4426950408889634f;

// ---------------------------------------------------------------- async 16B global->LDS
DI void async16(void* lds, const void* g) {
  __builtin_amdgcn_global_load_lds(
      (const __attribute__((address_space(1))) void*)g,
      (__attribute__((address_space(3))) void*)lds, 16, 0, 0);
}

// ---------------------------------------------------------------- fp32 -> bf16 fused converters
DI void cvt_one(const float* __restrict__ in, __bf16* __restrict__ out, int i) {
  const f32x4* in4 = (const f32x4*)in;
  f32x4 a = in4[2 * i], b = in4[2 * i + 1];
  bf16x8 o;
#pragma unroll
  for (int j = 0; j < 4; ++j) { o[j] = (__bf16)a[j]; o[4 + j] = (__bf16)b[j]; }
  ((bf16x8*)out)[i] = o;
}

__global__ void cvt3(const float* __restrict__ a, const float* __restrict__ b,
                     const float* __restrict__ c, __bf16* __restrict__ oa,
                     __bf16* __restrict__ ob, __bf16* __restrict__ oc, int n8) {
  int i = blockIdx.x * blockDim.x + threadIdx.x;
  if (i >= n8) return;
  cvt_one(a, oa, i); cvt_one(b, ob, i); cvt_one(c, oc, i);
}

__global__ void cvt4(const float* __restrict__ a, const float* __restrict__ b,
                     const float* __restrict__ c, const float* __restrict__ d,
                     __bf16* __restrict__ oa, __bf16* __restrict__ ob,
                     __bf16* __restrict__ oc, __bf16* __restrict__ od, int n8) {
  int i = blockIdx.x * blockDim.x + threadIdx.x;
  if (i >= n8) return;
  cvt_one(a, oa, i); cvt_one(b, ob, i); cvt_one(c, oc, i); cvt_one(d, od, i);
}

// ---------------------------------------------------------------- mask int32 -> bitmask
__global__ void pack_mask(const int* __restrict__ m, unsigned long long* __restrict__ bits) {
  const int total = Bc * Sc * Sc;
  const int nth = gridDim.x * blockDim.x;
  for (int i = blockIdx.x * blockDim.x + threadIdx.x; i < total; i += nth) {
    unsigned long long b = __ballot(m[i] != 0);
    if ((threadIdx.x & 63) == 0) bits[i >> 6] = b;
  }
}

// ---------------------------------------------------------------- GEMM core: 128x128 tile, K=1024
// 2-phase double-buffer: stage tile k+1 BEFORE computing tile k; one barrier per K-step.
DI void gemm_core(const __bf16* __restrict__ A, const __bf16* __restrict__ Bw,
                  __bf16* As, __bf16* Bs, int m0, int n0, int t, f32x4 (&acc)[4][4]) {
  const int lane = t & 63, wv = t >> 6;
  const int lo = lane & 15, hi = lane >> 4;
  const int wm = (wv >> 1) * 64, wn = (wv & 1) * 64;
  const int rowA = t >> 2, kc8 = (t & 3) * 8;

  auto stage = [&](int buf, int k0) {
    __bf16* as = As + buf * 4096;
    __bf16* bs = Bs + buf * 4096;
    async16(&as[t * 8],        A  + (size_t)(m0 + rowA) * 1024      + k0 + kc8);
    async16(&as[t * 8 + 2048], A  + (size_t)(m0 + rowA + 64) * 1024 + k0 + kc8);
    async16(&bs[t * 8],        Bw + (size_t)(n0 + rowA) * 1024      + k0 + kc8);
    async16(&bs[t * 8 + 2048], Bw + (size_t)(n0 + rowA + 64) * 1024 + k0 + kc8);
  };

  stage(0, 0);
  __syncthreads();                          // drain prologue loads (vmcnt 0 + barrier)
  int cur = 0;
  for (int k0 = 0; k0 < 1024; k0 += 32) {
    if (k0 + 32 < 1024) stage(cur ^ 1, k0 + 32);   // prefetch next tile (hidden under compute)
    const __bf16* as = As + cur * 4096;
    const __bf16* bs = Bs + cur * 4096;
    bf16x8 af[4], bfr[4];
#pragma unroll
    for (int i = 0; i < 4; ++i)
      af[i] = *(const bf16x8*)&as[(wm + i * 16 + lo) * 32 + hi * 8];
#pragma unroll
    for (int j = 0; j < 4; ++j)
      bfr[j] = *(const bf16x8*)&bs[(wn + j * 16 + lo) * 32 + hi * 8];
#pragma unroll
    for (int i = 0; i < 4; ++i)
#pragma unroll
      for (int j = 0; j < 4; ++j)
        acc[i][j] = __builtin_amdgcn_mfma_f32_16x16x32_bf16(af[i], bfr[j], acc[i][j], 0, 0, 0);
    __syncthreads();                        // drains prefetch; protects buf cur for re-stage
    cur ^= 1;
  }
}

// ---------------------------------------------------------------- fused QKV projection
// which=0: Q*0.125 -> Qh [B][H][S][64] ; which=1: K -> Kh same ; which=2: V -> Vt [B][H][64][S]
__global__ __launch_bounds__(256, 4)
void gemm_qkv(const __bf16* __restrict__ Aq, const __bf16* __restrict__ Ak,
              const __bf16* __restrict__ Av, const __bf16* __restrict__ Wqb,
              const __bf16* __restrict__ Wkb, const __bf16* __restrict__ Wvb,
              const float* __restrict__ bq, const float* __restrict__ bk,
              const float* __restrict__ bv,
              __bf16* __restrict__ Qh, __bf16* __restrict__ Kh, __bf16* __restrict__ Vt) {
  __shared__ __bf16 As[2][128 * 32];
  __shared__ __bf16 Bs[2][128 * 32];
  const int which = blockIdx.x >> 8;          // 3 GEMMs of 256 tiles each
  int local = blockIdx.x & 255;
  local = (local & 7) * 32 + (local >> 3);    // XCD-contiguous swizzle (XCD = origIdx&7)
  const int m0 = (local >> 3) * 128, n0 = (local & 7) * 128;
  const __bf16* A    = which == 0 ? Aq  : which == 1 ? Ak  : Av;
  const __bf16* Bw   = which == 0 ? Wqb : which == 1 ? Wkb : Wvb;
  const float*  bias = which == 0 ? bq  : which == 1 ? bk  : bv;
  const int t = threadIdx.x;

  f32x4 acc[4][4] = {};
  gemm_core(A, Bw, &As[0][0], &Bs[0][0], m0, n0, t, acc);

  const int lane = t & 63, wv = t >> 6, lo = lane & 15, hi = lane >> 4;
  const int wm = (wv >> 1) * 64, wn = (wv & 1) * 64;

  if (which < 2) {
    __bf16* C = which ? Kh : Qh;              // head-major [B][H][S][64]
    const float scl = which == 0 ? 0.125f : 1.0f;   // fold 1/sqrt(d_k) into Q
#pragma unroll
    for (int mi = 0; mi < 4; ++mi) {
      const int mbase = m0 + wm + mi * 16 + hi * 4;
      const int b = mbase >> 11, s = mbase & 2047;
#pragma unroll
      for (int ni = 0; ni < 4; ++ni) {
        const int n = n0 + wn + ni * 16 + lo;
        const int h = n >> 6, d = n & 63;
        const float bb = bias[n];
        __bf16* p = C + ((size_t)(b * Hc + h) * Sc + s) * 64 + d;
#pragma unroll
        for (int r = 0; r < 4; ++r)
          p[(size_t)r * 64] = (__bf16)((acc[mi][ni][r] + bb) * scl);
      }
    }
  } else {                                    // V transposed [B][H][64][S]
#pragma unroll
    for (int mi = 0; mi < 4; ++mi) {
      const int mbase = m0 + wm + mi * 16 + hi * 4;
      const int b = mbase >> 11, s0 = mbase & 2047;
#pragma unroll
      for (int ni = 0; ni < 4; ++ni) {
        const int n = n0 + wn + ni * 16 + lo;
        const int h = n >> 6, d = n & 63;
        const float bb = bias[n];
        bf16x4 pk;
#pragma unroll
        for (int r = 0; r < 4; ++r) pk[r] = (__bf16)(acc[mi][ni][r] + bb);
        *(bf16x4*)(Vt + ((size_t)(b * Hc + h) * 64 + d) * Sc + s0) = pk;
      }
    }
  }
}

// ---------------------------------------------------------------- output projection (fp32 out)
__global__ __launch_bounds__(256, 4)
void gemm_o(const __bf16* __restrict__ A, const __bf16* __restrict__ Bw,
            const float* __restrict__ bias, float* __restrict__ C) {
  __shared__ __bf16 As[2][128 * 32];
  __shared__ __bf16 Bs[2][128 * 32];
  int bid = blockIdx.x;
  bid = (bid & 7) * 32 + (bid >> 3);
  const int m0 = (bid >> 3) * 128, n0 = (bid & 7) * 128;
  const int t = threadIdx.x;

  f32x4 acc[4][4] = {};
  gemm_core(A, Bw, &As[0][0], &Bs[0][0], m0, n0, t, acc);

  const int lane = t & 63, wv = t >> 6, lo = lane & 15, hi = lane >> 4;
  const int wm = (wv >> 1) * 64, wn = (wv & 1) * 64;
#pragma unroll
  for (int mi = 0; mi < 4; ++mi) {
    const int mbase = m0 + wm + mi * 16 + hi * 4;
#pragma unroll
    for (int ni = 0; ni < 4; ++ni) {
      const int n = n0 + wn + ni * 16 + lo;
      const float bb = bias[n];
#pragma unroll
      for (int r = 0; r < 4; ++r)
        C[(size_t)(mbase + r) * 1024 + n] = acc[mi][ni][r] + bb;
    }
  }
}

// ---------------------------------------------------------------- flash attention, swapped QK^T
// Qh (pre-scaled by 0.125), Kh: [B][H][S][64] ; Vt: [B][H][64][S] ; X: [B*S][1024] bf16
// 8 waves x 16 q-rows = 128 q (512 threads). K/V read DIRECTLY from global (L2-resident;
// staging removed per common-mistake #7) -> no barriers in main loop, LDS = P only,
// 4 blocks/CU (wave cap). Lane owns q-row lo; S^T = mfma(K,Q); softmax in-lane + 2 shfl.
__global__ __launch_bounds__(512, 8)
void attn_fwd(const __bf16* __restrict__ Qh, const __bf16* __restrict__ Kh,
              const __bf16* __restrict__ Vt, const unsigned long long* __restrict__ mbits,
              __bf16* __restrict__ X) {
  __shared__ __bf16 Pq[8][16][68];            // stride 34 dwords (≡2 mod 32): bank-floor on
                                              // b64 writes (4/bank) and b128 reads (8/bank)
  int bid = blockIdx.x;
  bid = (bid & 7) * 64 + (bid >> 3);          // XCD swizzle: per-XCD 4 heads (2MB K/V, L2-fits)
  const int qblk = bid & 15, h = (bid >> 4) & 15, b = bid >> 8;
  const int t = threadIdx.x, lane = t & 63, wv = t >> 6;
  const int lo = lane & 15, hi = lane >> 4;
  const int q0 = qblk * 128 + wv * 16;

  const size_t headoff = (size_t)(b * Hc + h) * Sc * 64;
  const __bf16* Qp = Qh + headoff + (size_t)q0 * 64;
  const __bf16* Kp = Kh + headoff;            // [S][64]
  const __bf16* Vp = Vt + headoff;            // [64][S]

  bf16x8 qf[2];
#pragma unroll
  for (int c = 0; c < 2; ++c)
    qf[c] = *(const bf16x8*)&Qp[lo * 64 + c * 32 + hi * 8];

  f32x4 o[4] = {};
  float mr = -1e30f, lr = 0.f;
  const unsigned long long* mrow = mbits + (size_t)(b * Sc + q0 + lo) * (Sc / 64);

  for (int kb = 0; kb < Sc; kb += 64) {
    // ---- S^T tile: 64 keys x 16 q, K straight from global (coalesced 16B/lane)
    f32x4 sc[4];
    __builtin_amdgcn_s_setprio(1);
#pragma unroll
    for (int kc = 0; kc < 4; ++kc) {
      const __bf16* kr = Kp + (size_t)(kb + kc * 16 + lo) * 64 + hi * 8;
      bf16x8 kf0 = *(const bf16x8*)kr;
      bf16x8 kf1 = *(const bf16x8*)(kr + 32);
      f32x4 z = {0.f, 0.f, 0.f, 0.f};
      sc[kc] = __builtin_amdgcn_mfma_f32_16x16x32_bf16(kf0, qf[0], z, 0, 0, 0);
      sc[kc] = __builtin_amdgcn_mfma_f32_16x16x32_bf16(kf1, qf[1], sc[kc], 0, 0, 0);
    }
    __builtin_amdgcn_s_setprio(0);

    const unsigned long long mb = mrow[kb >> 6];
    if (!__all(mb == ~0ull)) {
#pragma unroll
      for (int kc = 0; kc < 4; ++kc)
#pragma unroll
        for (int r = 0; r < 4; ++r)
          if (!((mb >> (kc * 16 + hi * 4 + r)) & 1ull)) sc[kc][r] = -1e-9f;
    }
    float pmax = -1e30f;
#pragma unroll
    for (int kc = 0; kc < 4; ++kc)
#pragma unroll
      for (int r = 0; r < 4; ++r) pmax = fmaxf(pmax, sc[kc][r]);
    pmax = fmaxf(pmax, __shfl_xor(pmax, 16));
    pmax = fmaxf(pmax, __shfl_xor(pmax, 32));

    if (!__all(pmax <= mr + 8.f)) {           // T13 defer-max
      const float mn = fmaxf(mr, pmax);
      const float fs = exp2f((mr - mn) * LOG2E);
      lr *= fs;
#pragma unroll
      for (int d0 = 0; d0 < 4; ++d0) o[d0] *= fs;
      mr = mn;
    }
    const float mj = mr * LOG2E;
    float rs = 0.f;
#pragma unroll
    for (int kc = 0; kc < 4; ++kc)
#pragma unroll
      for (int r = 0; r < 4; ++r) {
        const float p = exp2f(__builtin_fmaf(sc[kc][r], LOG2E, -mj));
        sc[kc][r] = p; rs += p;
      }
    rs += __shfl_xor(rs, 16);
    rs += __shfl_xor(rs, 32);
    lr += rs;

#pragma unroll
    for (int kc = 0; kc < 4; ++kc) {          // P[q][k] -> LDS, 4x ds_write_b64
      bf16x4 pk;
#pragma unroll
      for (int r = 0; r < 4; ++r) pk[r] = (__bf16)sc[kc][r];
      *(bf16x4*)&Pq[wv][lo][kc * 16 + hi * 4] = pk;
    }
    bf16x8 pa0 = *(const bf16x8*)&Pq[wv][lo][hi * 8];
    bf16x8 pa1 = *(const bf16x8*)&Pq[wv][lo][32 + hi * 8];

    // ---- O += P V, V^T straight from global (contiguous 16B/lane, L1/L2-hot)
    __builtin_amdgcn_s_setprio(1);
#pragma unroll
    for (int d0 = 0; d0 < 4; ++d0) {
      const __bf16* vr = Vp + (size_t)(d0 * 16 + lo) * Sc + kb + hi * 8;
      bf16x8 vf0 = *(const bf16x8*)vr;
      bf16x8 vf1 = *(const bf16x8*)(vr + 32);
      o[d0] = __builtin_amdgcn_mfma_f32_16x16x32_bf16(vf0, pa0, o[d0], 0, 0, 0);
      o[d0] = __builtin_amdgcn_mfma_f32_16x16x32_bf16(vf1, pa1, o[d0], 0, 0, 0);
    }
    __builtin_amdgcn_s_setprio(0);
  }

  const float inv = 1.f / lr;
#pragma unroll
  for (int d0 = 0; d0 < 4; ++d0) {
    bf16x4 st;
#pragma unroll
    for (int r = 0; r < 4; ++r) st[r] = (__bf16)(o[d0][r] * inv);
    *(bf16x4*)&X[(size_t)(b * Sc + q0 + lo) * 1024 + h * 64 + d0 * 16 + hi * 4] = st;
  }
}

// ---------------------------------------------------------------- launcher
extern "C" void kernel_launch(void* const* d_in, const int* in_sizes, int n_in,
                              void* d_out, int out_size, void* d_ws, size_t ws_size,
                              hipStream_t stream) {
  const float* q  = (const float*)d_in[0];
  const float* k  = (const float*)d_in[1];
  const float* v  = (const float*)d_in[2];
  const int*   mask = (const int*)d_in[3];
  const float* Wq = (const float*)d_in[4];
  const float* bq = (const float*)d_in[5];
  const float* Wk = (const float*)d_in[6];
  const float* bk = (const float*)d_in[7];
  const float* Wv = (const float*)d_in[8];
  const float* bv = (const float*)d_in[9];
  const float* Wo = (const float*)d_in[10];
  const float* bo = (const float*)d_in[11];

  const size_t MB = 1u << 20;
  if (ws_size < 66 * MB) return;

  char* ws = (char*)d_ws;
  __bf16* wqb  = (__bf16*)(ws + 0 * MB);
  __bf16* wkb  = (__bf16*)(ws + 2 * MB);
  __bf16* wvb  = (__bf16*)(ws + 4 * MB);
  __bf16* wob  = (__bf16*)(ws + 6 * MB);
  __bf16* qbin = (__bf16*)(ws + 8 * MB);
  __bf16* kbin = (__bf16*)(ws + 16 * MB);
  __bf16* vbin = (__bf16*)(ws + 24 * MB);
  __bf16* Qh   = (__bf16*)(ws + 32 * MB);
  __bf16* Kh   = (__bf16*)(ws + 40 * MB);
  __bf16* Vt   = (__bf16*)(ws + 48 * MB);
  __bf16* Xat  = (__bf16*)(ws + 56 * MB);
  unsigned long long* mbits = (unsigned long long*)(ws + 64 * MB);

  const int nIn8 = Mrows * Dm / 8;   // 524288
  const int nW8  = Dm * Dm / 8;      // 131072
  cvt3<<<nIn8 / 256, 256, 0, stream>>>(q, k, v, qbin, kbin, vbin, nIn8);
  cvt4<<<nW8 / 256, 256, 0, stream>>>(Wq, Wk, Wv, Wo, wqb, wkb, wvb, wob, nW8);
  pack_mask<<<4096, 256, 0, stream>>>(mask, mbits);

  gemm_qkv<<<768, 256, 0, stream>>>(qbin, kbin, vbin, wqb, wkb, wvb, bq, bk, bv, Qh, Kh, Vt);

  attn_fwd<<<512, 512, 0, stream>>>(Qh, Kh, Vt, mbits, Xat);

  gemm_o<<<256, 256, 0, stream>>>(Xat, wob, bo, (float*)d_out);
}

// Round 9
// 451.162 us; speedup vs baseline: 1.0101x; 1.0101x over previous
//
#include <hip/hip_runtime.h>
#include <hip/hip_bf16.h>
#include <stdint.h>

#define DI __device__ __forceinline__

typedef __bf16 bf16x8 __attribute__((ext_vector_type(8)));
typedef __bf16 bf16x4 __attribute__((ext_vector_type(4)));
typedef float  f32x4  __attribute__((ext_vector_type(4)));

constexpr int Bc = 2, Sc = 2048, Dm = 1024, Hc = 16;
constexpr int Mrows = Bc * Sc;          // 4096
constexpr float LOG2E = 1.4426950408889634f;

// ---------------------------------------------------------------- async 16B global->LDS
DI void async16(void* lds, const void* g) {
  __builtin_amdgcn_global_load_lds(
      (const __attribute__((address_space(1))) void*)g,
      (__attribute__((address_space(3))) void*)lds, 16, 0, 0);
}

// ---------------------------------------------------------------- fp32 -> bf16 fused converters
DI void cvt_one(const float* __restrict__ in, __bf16* __restrict__ out, int i) {
  const f32x4* in4 = (const f32x4*)in;
  f32x4 a = in4[2 * i], b = in4[2 * i + 1];
  bf16x8 o;
#pragma unroll
  for (int j = 0; j < 4; ++j) { o[j] = (__bf16)a[j]; o[4 + j] = (__bf16)b[j]; }
  ((bf16x8*)out)[i] = o;
}

__global__ void cvt3(const float* __restrict__ a, const float* __restrict__ b,
                     const float* __restrict__ c, __bf16* __restrict__ oa,
                     __bf16* __restrict__ ob, __bf16* __restrict__ oc, int n8) {
  int i = blockIdx.x * blockDim.x + threadIdx.x;
  if (i >= n8) return;
  cvt_one(a, oa, i); cvt_one(b, ob, i); cvt_one(c, oc, i);
}

__global__ void cvt4(const float* __restrict__ a, const float* __restrict__ b,
                     const float* __restrict__ c, const float* __restrict__ d,
                     __bf16* __restrict__ oa, __bf16* __restrict__ ob,
                     __bf16* __restrict__ oc, __bf16* __restrict__ od, int n8) {
  int i = blockIdx.x * blockDim.x + threadIdx.x;
  if (i >= n8) return;
  cvt_one(a, oa, i); cvt_one(b, ob, i); cvt_one(c, oc, i); cvt_one(d, od, i);
}

// ---------------------------------------------------------------- mask int32 -> bitmask
__global__ void pack_mask(const int* __restrict__ m, unsigned long long* __restrict__ bits) {
  const int total = Bc * Sc * Sc;
  const int nth = gridDim.x * blockDim.x;
  for (int i = blockIdx.x * blockDim.x + threadIdx.x; i < total; i += nth) {
    unsigned long long b = __ballot(m[i] != 0);
    if ((threadIdx.x & 63) == 0) bits[i >> 6] = b;
  }
}

// ---------------------------------------------------------------- GEMM core: 128x128 tile, K=1024
// 2-phase double-buffer: stage tile k+1 BEFORE computing tile k; one barrier per K-step.
DI void gemm_core(const __bf16* __restrict__ A, const __bf16* __restrict__ Bw,
                  __bf16* As, __bf16* Bs, int m0, int n0, int t, f32x4 (&acc)[4][4]) {
  const int lane = t & 63, wv = t >> 6;
  const int lo = lane & 15, hi = lane >> 4;
  const int wm = (wv >> 1) * 64, wn = (wv & 1) * 64;
  const int rowA = t >> 2, kc8 = (t & 3) * 8;

  auto stage = [&](int buf, int k0) {
    __bf16* as = As + buf * 4096;
    __bf16* bs = Bs + buf * 4096;
    async16(&as[t * 8],        A  + (size_t)(m0 + rowA) * 1024      + k0 + kc8);
    async16(&as[t * 8 + 2048], A  + (size_t)(m0 + rowA + 64) * 1024 + k0 + kc8);
    async16(&bs[t * 8],        Bw + (size_t)(n0 + rowA) * 1024      + k0 + kc8);
    async16(&bs[t * 8 + 2048], Bw + (size_t)(n0 + rowA + 64) * 1024 + k0 + kc8);
  };

  stage(0, 0);
  __syncthreads();                          // drain prologue loads (vmcnt 0 + barrier)
  int cur = 0;
  for (int k0 = 0; k0 < 1024; k0 += 32) {
    if (k0 + 32 < 1024) stage(cur ^ 1, k0 + 32);   // prefetch next tile (hidden under compute)
    const __bf16* as = As + cur * 4096;
    const __bf16* bs = Bs + cur * 4096;
    bf16x8 af[4], bfr[4];
#pragma unroll
    for (int i = 0; i < 4; ++i)
      af[i] = *(const bf16x8*)&as[(wm + i * 16 + lo) * 32 + hi * 8];
#pragma unroll
    for (int j = 0; j < 4; ++j)
      bfr[j] = *(const bf16x8*)&bs[(wn + j * 16 + lo) * 32 + hi * 8];
#pragma unroll
    for (int i = 0; i < 4; ++i)
#pragma unroll
      for (int j = 0; j < 4; ++j)
        acc[i][j] = __builtin_amdgcn_mfma_f32_16x16x32_bf16(af[i], bfr[j], acc[i][j], 0, 0, 0);
    __syncthreads();                        // drains prefetch; protects buf cur for re-stage
    cur ^= 1;
  }
}

// ---------------------------------------------------------------- fused QKV projection
// which=0: Q*0.125 -> Qh [B][H][S][64] ; which=1: K -> Kh same ; which=2: V -> Vt [B][H][64][S]
__global__ __launch_bounds__(256, 4)
void gemm_qkv(const __bf16* __restrict__ Aq, const __bf16* __restrict__ Ak,
              const __bf16* __restrict__ Av, const __bf16* __restrict__ Wqb,
              const __bf16* __restrict__ Wkb, const __bf16* __restrict__ Wvb,
              const float* __restrict__ bq, const float* __restrict__ bk,
              const float* __restrict__ bv,
              __bf16* __restrict__ Qh, __bf16* __restrict__ Kh, __bf16* __restrict__ Vt) {
  __shared__ __bf16 As[2][128 * 32];
  __shared__ __bf16 Bs[2][128 * 32];
  const int which = blockIdx.x >> 8;          // 3 GEMMs of 256 tiles each
  int local = blockIdx.x & 255;
  local = (local & 7) * 32 + (local >> 3);    // XCD-contiguous swizzle (XCD = origIdx&7)
  const int m0 = (local >> 3) * 128, n0 = (local & 7) * 128;
  const __bf16* A    = which == 0 ? Aq  : which == 1 ? Ak  : Av;
  const __bf16* Bw   = which == 0 ? Wqb : which == 1 ? Wkb : Wvb;
  const float*  bias = which == 0 ? bq  : which == 1 ? bk  : bv;
  const int t = threadIdx.x;

  f32x4 acc[4][4] = {};
  gemm_core(A, Bw, &As[0][0], &Bs[0][0], m0, n0, t, acc);

  const int lane = t & 63, wv = t >> 6, lo = lane & 15, hi = lane >> 4;
  const int wm = (wv >> 1) * 64, wn = (wv & 1) * 64;

  if (which < 2) {
    __bf16* C = which ? Kh : Qh;              // head-major [B][H][S][64]
    const float scl = which == 0 ? 0.125f : 1.0f;   // fold 1/sqrt(d_k) into Q
#pragma unroll
    for (int mi = 0; mi < 4; ++mi) {
      const int mbase = m0 + wm + mi * 16 + hi * 4;
      const int b = mbase >> 11, s = mbase & 2047;
#pragma unroll
      for (int ni = 0; ni < 4; ++ni) {
        const int n = n0 + wn + ni * 16 + lo;
        const int h = n >> 6, d = n & 63;
        const float bb = bias[n];
        __bf16* p = C + ((size_t)(b * Hc + h) * Sc + s) * 64 + d;
#pragma unroll
        for (int r = 0; r < 4; ++r)
          p[(size_t)r * 64] = (__bf16)((acc[mi][ni][r] + bb) * scl);
      }
    }
  } else {                                    // V transposed [B][H][64][S]
#pragma unroll
    for (int mi = 0; mi < 4; ++mi) {
      const int mbase = m0 + wm + mi * 16 + hi * 4;
      const int b = mbase >> 11, s0 = mbase & 2047;
#pragma unroll
      for (int ni = 0; ni < 4; ++ni) {
        const int n = n0 + wn + ni * 16 + lo;
        const int h = n >> 6, d = n & 63;
        const float bb = bias[n];
        bf16x4 pk;
#pragma unroll
        for (int r = 0; r < 4; ++r) pk[r] = (__bf16)(acc[mi][ni][r] + bb);
        *(bf16x4*)(Vt + ((size_t)(b * Hc + h) * 64 + d) * Sc + s0) = pk;
      }
    }
  }
}

// ---------------------------------------------------------------- output projection (fp32 out)
__global__ __launch_bounds__(256, 4)
void gemm_o(const __bf16* __restrict__ A, const __bf16* __restrict__ Bw,
            const float* __restrict__ bias, float* __restrict__ C) {
  __shared__ __bf16 As[2][128 * 32];
  __shared__ __bf16 Bs[2][128 * 32];
  int bid = blockIdx.x;
  bid = (bid & 7) * 32 + (bid >> 3);
  const int m0 = (bid >> 3) * 128, n0 = (bid & 7) * 128;
  const int t = threadIdx.x;

  f32x4 acc[4][4] = {};
  gemm_core(A, Bw, &As[0][0], &Bs[0][0], m0, n0, t, acc);

  const int lane = t & 63, wv = t >> 6, lo = lane & 15, hi = lane >> 4;
  const int wm = (wv >> 1) * 64, wn = (wv & 1) * 64;
#pragma unroll
  for (int mi = 0; mi < 4; ++mi) {
    const int mbase = m0 + wm + mi * 16 + hi * 4;
#pragma unroll
    for (int ni = 0; ni < 4; ++ni) {
      const int n = n0 + wn + ni * 16 + lo;
      const float bb = bias[n];
#pragma unroll
      for (int r = 0; r < 4; ++r)
        C[(size_t)(mbase + r) * 1024 + n] = acc[mi][ni][r] + bb;
    }
  }
}

// ---------------------------------------------------------------- flash attention, swapped QK^T
// Qh (pre-scaled by 0.125), Kh: [B][H][S][64] ; Vt: [B][H][64][S] ; X: [B*S][1024] bf16
// 8 waves x 16 q-rows = 128 q (512 threads). K/V read DIRECTLY from global (L2-resident).
// No barriers in main loop; LDS = P only (bank-conflict-free, measured 0 in R6).
// launch_bounds (512,4): VGPR cap 128 — (512,8) forced a 64-reg ceiling and spilled
// (R6: VGPR=32, WRITE_SIZE 44MB of scratch, 3x slowdown). Do NOT raise to 8.
__global__ __launch_bounds__(512, 4)
void attn_fwd(const __bf16* __restrict__ Qh, const __bf16* __restrict__ Kh,
              const __bf16* __restrict__ Vt, const unsigned long long* __restrict__ mbits,
              __bf16* __restrict__ X) {
  __shared__ __bf16 Pq[8][16][68];            // stride 34 dwords (≡2 mod 32): bank-floor on
                                              // b64 writes (4/bank) and b128 reads (8/bank)
  int bid = blockIdx.x;
  bid = (bid & 7) * 64 + (bid >> 3);          // XCD swizzle: per-XCD 4 heads (2MB K/V, L2-fits)
  const int qblk = bid & 15, h = (bid >> 4) & 15, b = bid >> 8;
  const int t = threadIdx.x, lane = t & 63, wv = t >> 6;
  const int lo = lane & 15, hi = lane >> 4;
  const int q0 = qblk * 128 + wv * 16;

  const size_t headoff = (size_t)(b * Hc + h) * Sc * 64;
  const __bf16* Qp = Qh + headoff + (size_t)q0 * 64;
  const __bf16* Kp = Kh + headoff;            // [S][64]
  const __bf16* Vp = Vt + headoff;            // [64][S]

  bf16x8 qf[2];
#pragma unroll
  for (int c = 0; c < 2; ++c)
    qf[c] = *(const bf16x8*)&Qp[lo * 64 + c * 32 + hi * 8];

  f32x4 o[4] = {};
  float mr = -1e30f, lr = 0.f;
  const unsigned long long* mrow = mbits + (size_t)(b * Sc + q0 + lo) * (Sc / 64);

  for (int kb = 0; kb < Sc; kb += 64) {
    // ---- S^T tile: 64 keys x 16 q, K straight from global (coalesced 16B/lane)
    f32x4 sc[4];
    __builtin_amdgcn_s_setprio(1);
#pragma unroll
    for (int kc = 0; kc < 4; ++kc) {
      const __bf16* kr = Kp + (size_t)(kb + kc * 16 + lo) * 64 + hi * 8;
      bf16x8 kf0 = *(const bf16x8*)kr;
      bf16x8 kf1 = *(const bf16x8*)(kr + 32);
      f32x4 z = {0.f, 0.f, 0.f, 0.f};
      sc[kc] = __builtin_amdgcn_mfma_f32_16x16x32_bf16(kf0, qf[0], z, 0, 0, 0);
      sc[kc] = __builtin_amdgcn_mfma_f32_16x16x32_bf16(kf1, qf[1], sc[kc], 0, 0, 0);
    }
    __builtin_amdgcn_s_setprio(0);

    const unsigned long long mb = mrow[kb >> 6];
    if (!__all(mb == ~0ull)) {
#pragma unroll
      for (int kc = 0; kc < 4; ++kc)
#pragma unroll
        for (int r = 0; r < 4; ++r)
          if (!((mb >> (kc * 16 + hi * 4 + r)) & 1ull)) sc[kc][r] = -1e-9f;
    }
    float pmax = -1e30f;
#pragma unroll
    for (int kc = 0; kc < 4; ++kc)
#pragma unroll
      for (int r = 0; r < 4; ++r) pmax = fmaxf(pmax, sc[kc][r]);
    pmax = fmaxf(pmax, __shfl_xor(pmax, 16));
    pmax = fmaxf(pmax, __shfl_xor(pmax, 32));

    if (!__all(pmax <= mr + 8.f)) {           // T13 defer-max
      const float mn = fmaxf(mr, pmax);
      const float fs = exp2f((mr - mn) * LOG2E);
      lr *= fs;
#pragma unroll
      for (int d0 = 0; d0 < 4; ++d0) o[d0] *= fs;
      mr = mn;
    }
    const float mj = mr * LOG2E;
    float rs = 0.f;
#pragma unroll
    for (int kc = 0; kc < 4; ++kc)
#pragma unroll
      for (int r = 0; r < 4; ++r) {
        const float p = exp2f(__builtin_fmaf(sc[kc][r], LOG2E, -mj));
        sc[kc][r] = p; rs += p;
      }
    rs += __shfl_xor(rs, 16);
    rs += __shfl_xor(rs, 32);
    lr += rs;

#pragma unroll
    for (int kc = 0; kc < 4; ++kc) {          // P[q][k] -> LDS, 4x ds_write_b64
      bf16x4 pk;
#pragma unroll
      for (int r = 0; r < 4; ++r) pk[r] = (__bf16)sc[kc][r];
      *(bf16x4*)&Pq[wv][lo][kc * 16 + hi * 4] = pk;
    }
    bf16x8 pa0 = *(const bf16x8*)&Pq[wv][lo][hi * 8];
    bf16x8 pa1 = *(const bf16x8*)&Pq[wv][lo][32 + hi * 8];

    // ---- O += P V, V^T straight from global (contiguous 16B/lane, L1/L2-hot)
    __builtin_amdgcn_s_setprio(1);
#pragma unroll
    for (int d0 = 0; d0 < 4; ++d0) {
      const __bf16* vr = Vp + (size_t)(d0 * 16 + lo) * Sc + kb + hi * 8;
      bf16x8 vf0 = *(const bf16x8*)vr;
      bf16x8 vf1 = *(const bf16x8*)(vr + 32);
      o[d0] = __builtin_amdgcn_mfma_f32_16x16x32_bf16(vf0, pa0, o[d0], 0, 0, 0);
      o[d0] = __builtin_amdgcn_mfma_f32_16x16x32_bf16(vf1, pa1, o[d0], 0, 0, 0);
    }
    __builtin_amdgcn_s_setprio(0);
  }

  const float inv = 1.f / lr;
#pragma unroll
  for (int d0 = 0; d0 < 4; ++d0) {
    bf16x4 st;
#pragma unroll
    for (int r = 0; r < 4; ++r) st[r] = (__bf16)(o[d0][r] * inv);
    *(bf16x4*)&X[(size_t)(b * Sc + q0 + lo) * 1024 + h * 64 + d0 * 16 + hi * 4] = st;
  }
}

// ---------------------------------------------------------------- launcher
extern "C" void kernel_launch(void* const* d_in, const int* in_sizes, int n_in,
                              void* d_out, int out_size, void* d_ws, size_t ws_size,
                              hipStream_t stream) {
  const float* q  = (const float*)d_in[0];
  const float* k  = (const float*)d_in[1];
  const float* v  = (const float*)d_in[2];
  const int*   mask = (const int*)d_in[3];
  const float* Wq = (const float*)d_in[4];
  const float* bq = (const float*)d_in[5];
  const float* Wk = (const float*)d_in[6];
  const float* bk = (const float*)d_in[7];
  const float* Wv = (const float*)d_in[8];
  const float* bv = (const float*)d_in[9];
  const float* Wo = (const float*)d_in[10];
  const float* bo = (const float*)d_in[11];

  const size_t MB = 1u << 20;
  if (ws_size < 66 * MB) return;

  char* ws = (char*)d_ws;
  __bf16* wqb  = (__bf16*)(ws + 0 * MB);
  __bf16* wkb  = (__bf16*)(ws + 2 * MB);
  __bf16* wvb  = (__bf16*)(ws + 4 * MB);
  __bf16* wob  = (__bf16*)(ws + 6 * MB);
  __bf16* qbin = (__bf16*)(ws + 8 * MB);
  __bf16* kbin = (__bf16*)(ws + 16 * MB);
  __bf16* vbin = (__bf16*)(ws + 24 * MB);
  __bf16* Qh   = (__bf16*)(ws + 32 * MB);
  __bf16* Kh   = (__bf16*)(ws + 40 * MB);
  __bf16* Vt   = (__bf16*)(ws + 48 * MB);
  __bf16* Xat  = (__bf16*)(ws + 56 * MB);
  unsigned long long* mbits = (unsigned long long*)(ws + 64 * MB);

  const int nIn8 = Mrows * Dm / 8;   // 524288
  const int nW8  = Dm * Dm / 8;      // 131072
  cvt3<<<nIn8 / 256, 256, 0, stream>>>(q, k, v, qbin, kbin, vbin, nIn8);
  cvt4<<<nW8 / 256, 256, 0, stream>>>(Wq, Wk, Wv, Wo, wqb, wkb, wvb, wob, nW8);
  pack_mask<<<4096, 256, 0, stream>>>(mask, mbits);

  gemm_qkv<<<768, 256, 0, stream>>>(qbin, kbin, vbin, wqb, wkb, wvb, bq, bk, bv, Qh, Kh, Vt);

  attn_fwd<<<512, 512, 0, stream>>>(Qh, Kh, Vt, mbits, Xat);

  gemm_o<<<256, 256, 0, stream>>>(Xat, wob, bo, (float*)d_out);
}

// Round 12
// 281.118 us; speedup vs baseline: 1.6211x; 1.6049x over previous
//
#include <hip/hip_runtime.h>
#include <hip/hip_bf16.h>
#include <stdint.h>

#define DI __device__ __forceinline__

typedef __bf16 bf16x8 __attribute__((ext_vector_type(8)));
typedef __bf16 bf16x4 __attribute__((ext_vector_type(4)));
typedef float  f32x4  __attribute__((ext_vector_type(4)));

constexpr int Bc = 2, Sc = 2048, Dm = 1024, Hc = 16;
constexpr int Mrows = Bc * Sc;          // 4096
constexpr float LOG2E = 1.4426950408889634f;

// ---------------------------------------------------------------- async 16B global->LDS
DI void async16(void* lds, const void* g) {
  __builtin_amdgcn_global_load_lds(
      (const __attribute__((address_space(1))) void*)g,
      (__attribute__((address_space(3))) void*)lds, 16, 0, 0);
}

// ---------------------------------------------------------------- fp32 -> bf16 fused converters
DI void cvt_one(const float* __restrict__ in, __bf16* __restrict__ out, int i) {
  const f32x4* in4 = (const f32x4*)in;
  f32x4 a = in4[2 * i], b = in4[2 * i + 1];
  bf16x8 o;
#pragma unroll
  for (int j = 0; j < 4; ++j) { o[j] = (__bf16)a[j]; o[4 + j] = (__bf16)b[j]; }
  ((bf16x8*)out)[i] = o;
}

__global__ void cvt3(const float* __restrict__ a, const float* __restrict__ b,
                     const float* __restrict__ c, __bf16* __restrict__ oa,
                     __bf16* __restrict__ ob, __bf16* __restrict__ oc, int n8) {
  int i = blockIdx.x * blockDim.x + threadIdx.x;
  if (i >= n8) return;
  cvt_one(a, oa, i); cvt_one(b, ob, i); cvt_one(c, oc, i);
}

__global__ void cvt4(const float* __restrict__ a, const float* __restrict__ b,
                     const float* __restrict__ c, const float* __restrict__ d,
                     __bf16* __restrict__ oa, __bf16* __restrict__ ob,
                     __bf16* __restrict__ oc, __bf16* __restrict__ od, int n8) {
  int i = blockIdx.x * blockDim.x + threadIdx.x;
  if (i >= n8) return;
  cvt_one(a, oa, i); cvt_one(b, ob, i); cvt_one(c, oc, i); cvt_one(d, od, i);
}

// ---------------------------------------------------------------- mask int32 -> bitmask
__global__ void pack_mask(const int* __restrict__ m, unsigned long long* __restrict__ bits) {
  const int total = Bc * Sc * Sc;
  const int nth = gridDim.x * blockDim.x;
  for (int i = blockIdx.x * blockDim.x + threadIdx.x; i < total; i += nth) {
    unsigned long long b = __ballot(m[i] != 0);
    if ((threadIdx.x & 63) == 0) bits[i >> 6] = b;
  }
}

// ---------------------------------------------------------------- GEMM core: 128x128 tile, K=1024
// 2-phase double-buffer: stage tile k+1 BEFORE computing tile k; one barrier per K-step.
DI void gemm_core(const __bf16* __restrict__ A, const __bf16* __restrict__ Bw,
                  __bf16* As, __bf16* Bs, int m0, int n0, int t, f32x4 (&acc)[4][4]) {
  const int lane = t & 63, wv = t >> 6;
  const int lo = lane & 15, hi = lane >> 4;
  const int wm = (wv >> 1) * 64, wn = (wv & 1) * 64;
  const int rowA = t >> 2, kc8 = (t & 3) * 8;

  auto stage = [&](int buf, int k0) {
    __bf16* as = As + buf * 4096;
    __bf16* bs = Bs + buf * 4096;
    async16(&as[t * 8],        A  + (size_t)(m0 + rowA) * 1024      + k0 + kc8);
    async16(&as[t * 8 + 2048], A  + (size_t)(m0 + rowA + 64) * 1024 + k0 + kc8);
    async16(&bs[t * 8],        Bw + (size_t)(n0 + rowA) * 1024      + k0 + kc8);
    async16(&bs[t * 8 + 2048], Bw + (size_t)(n0 + rowA + 64) * 1024 + k0 + kc8);
  };

  stage(0, 0);
  __syncthreads();                          // drain prologue loads (vmcnt 0 + barrier)
  int cur = 0;
  for (int k0 = 0; k0 < 1024; k0 += 32) {
    if (k0 + 32 < 1024) stage(cur ^ 1, k0 + 32);   // prefetch next tile (hidden under compute)
    const __bf16* as = As + cur * 4096;
    const __bf16* bs = Bs + cur * 4096;
    bf16x8 af[4], bfr[4];
#pragma unroll
    for (int i = 0; i < 4; ++i)
      af[i] = *(const bf16x8*)&as[(wm + i * 16 + lo) * 32 + hi * 8];
#pragma unroll
    for (int j = 0; j < 4; ++j)
      bfr[j] = *(const bf16x8*)&bs[(wn + j * 16 + lo) * 32 + hi * 8];
#pragma unroll
    for (int i = 0; i < 4; ++i)
#pragma unroll
      for (int j = 0; j < 4; ++j)
        acc[i][j] = __builtin_amdgcn_mfma_f32_16x16x32_bf16(af[i], bfr[j], acc[i][j], 0, 0, 0);
    __syncthreads();                        // drains prefetch; protects buf cur for re-stage
    cur ^= 1;
  }
}

// ---------------------------------------------------------------- fused QKV projection
// which=0: Q*0.125 -> Qh [B][H][S][64] ; which=1: K -> Kh same ; which=2: V -> Vt [B][H][64][S]
__global__ __launch_bounds__(256, 4)
void gemm_qkv(const __bf16* __restrict__ Aq, const __bf16* __restrict__ Ak,
              const __bf16* __restrict__ Av, const __bf16* __restrict__ Wqb,
              const __bf16* __restrict__ Wkb, const __bf16* __restrict__ Wvb,
              const float* __restrict__ bq, const float* __restrict__ bk,
              const float* __restrict__ bv,
              __bf16* __restrict__ Qh, __bf16* __restrict__ Kh, __bf16* __restrict__ Vt) {
  __shared__ __bf16 As[2][128 * 32];
  __shared__ __bf16 Bs[2][128 * 32];
  const int which = blockIdx.x >> 8;          // 3 GEMMs of 256 tiles each
  int local = blockIdx.x & 255;
  local = (local & 7) * 32 + (local >> 3);    // XCD-contiguous swizzle (XCD = origIdx&7)
  const int m0 = (local >> 3) * 128, n0 = (local & 7) * 128;
  const __bf16* A    = which == 0 ? Aq  : which == 1 ? Ak  : Av;
  const __bf16* Bw   = which == 0 ? Wqb : which == 1 ? Wkb : Wvb;
  const float*  bias = which == 0 ? bq  : which == 1 ? bk  : bv;
  const int t = threadIdx.x;

  f32x4 acc[4][4] = {};
  gemm_core(A, Bw, &As[0][0], &Bs[0][0], m0, n0, t, acc);

  const int lane = t & 63, wv = t >> 6, lo = lane & 15, hi = lane >> 4;
  const int wm = (wv >> 1) * 64, wn = (wv & 1) * 64;

  if (which < 2) {
    __bf16* C = which ? Kh : Qh;              // head-major [B][H][S][64]
    const float scl = which == 0 ? 0.125f : 1.0f;   // fold 1/sqrt(d_k) into Q
#pragma unroll
    for (int mi = 0; mi < 4; ++mi) {
      const int mbase = m0 + wm + mi * 16 + hi * 4;
      const int b = mbase >> 11, s = mbase & 2047;
#pragma unroll
      for (int ni = 0; ni < 4; ++ni) {
        const int n = n0 + wn + ni * 16 + lo;
        const int h = n >> 6, d = n & 63;
        const float bb = bias[n];
        __bf16* p = C + ((size_t)(b * Hc + h) * Sc + s) * 64 + d;
#pragma unroll
        for (int r = 0; r < 4; ++r)
          p[(size_t)r * 64] = (__bf16)((acc[mi][ni][r] + bb) * scl);
      }
    }
  } else {                                    // V transposed [B][H][64][S]
#pragma unroll
    for (int mi = 0; mi < 4; ++mi) {
      const int mbase = m0 + wm + mi * 16 + hi * 4;
      const int b = mbase >> 11, s0 = mbase & 2047;
#pragma unroll
      for (int ni = 0; ni < 4; ++ni) {
        const int n = n0 + wn + ni * 16 + lo;
        const int h = n >> 6, d = n & 63;
        const float bb = bias[n];
        bf16x4 pk;
#pragma unroll
        for (int r = 0; r < 4; ++r) pk[r] = (__bf16)(acc[mi][ni][r] + bb);
        *(bf16x4*)(Vt + ((size_t)(b * Hc + h) * 64 + d) * Sc + s0) = pk;
      }
    }
  }
}

// ---------------------------------------------------------------- output projection (fp32 out)
__global__ __launch_bounds__(256, 4)
void gemm_o(const __bf16* __restrict__ A, const __bf16* __restrict__ Bw,
            const float* __restrict__ bias, float* __restrict__ C) {
  __shared__ __bf16 As[2][128 * 32];
  __shared__ __bf16 Bs[2][128 * 32];
  int bid = blockIdx.x;
  bid = (bid & 7) * 32 + (bid >> 3);
  const int m0 = (bid >> 3) * 128, n0 = (bid & 7) * 128;
  const int t = threadIdx.x;

  f32x4 acc[4][4] = {};
  gemm_core(A, Bw, &As[0][0], &Bs[0][0], m0, n0, t, acc);

  const int lane = t & 63, wv = t >> 6, lo = lane & 15, hi = lane >> 4;
  const int wm = (wv >> 1) * 64, wn = (wv & 1) * 64;
#pragma unroll
  for (int mi = 0; mi < 4; ++mi) {
    const int mbase = m0 + wm + mi * 16 + hi * 4;
#pragma unroll
    for (int ni = 0; ni < 4; ++ni) {
      const int n = n0 + wn + ni * 16 + lo;
      const float bb = bias[n];
#pragma unroll
      for (int r = 0; r < 4; ++r)
        C[(size_t)(mbase + r) * 1024 + n] = acc[mi][ni][r] + bb;
    }
  }
}

// ---------------------------------------------------------------- flash attention, swapped QK^T
// Qh (pre-scaled by 0.125), Kh: [B][H][S][64] ; Vt: [B][H][64][S] ; X: [B*S][1024] bf16
// 8 waves x 16 q-rows = 128 q (512 threads).
// K/V STAGED in LDS, double-buffered, shared by all 8 waves — direct-global was a 3x
// regression (R9: 255us, latency-bound, MfmaUtil 5.5%): 8 waves re-reading the same
// L2-resident tile expose ~200cy L2 latency on the QK^T critical path every iter.
// Staging amortizes it 8x and the dbuf prefetch hides it (R4: 85us).
// One barrier per iter (barrier-top schedule: all reads of buf B done before restage).
// Pq stride 68 (34 dwords == 2 mod 32): measured 0 bank conflicts in R9.
// launch_bounds (512,4): (512,8) forces 64-VGPR ceiling -> spills (R6). Do NOT raise.
__global__ __launch_bounds__(512, 4)
void attn_fwd(const __bf16* __restrict__ Qh, const __bf16* __restrict__ Kh,
              const __bf16* __restrict__ Vt, const unsigned long long* __restrict__ mbits,
              __bf16* __restrict__ X) {
  __shared__ __bf16 Ks[2][64 * 64];           // 8KB x2, XOR-swizzled cols
  __shared__ __bf16 Vs[2][64 * 64];           // 8KB x2, XOR-swizzled cols
  __shared__ __bf16 Pq[8][16][68];            // per-wave P, stride 68: 0 conflicts (R9)

  int bid = blockIdx.x;
  bid = (bid & 7) * 64 + (bid >> 3);          // XCD swizzle: per-XCD 4 heads (2MB K/V, L2-fits)
  const int qblk = bid & 15, h = (bid >> 4) & 15, b = bid >> 8;
  const int t = threadIdx.x, lane = t & 63, wv = t >> 6;
  const int lo = lane & 15, hi = lane >> 4;
  const int q0 = qblk * 128 + wv * 16;

  const size_t headoff = (size_t)(b * Hc + h) * Sc * 64;
  const __bf16* Qp = Qh + headoff + (size_t)q0 * 64;
  const __bf16* Kp = Kh + headoff;            // [S][64]
  const __bf16* Vp = Vt + headoff;            // [64][S]

  bf16x8 qf[2];
#pragma unroll
  for (int c = 0; c < 2; ++c)
    qf[c] = *(const bf16x8*)&Qp[lo * 64 + c * 32 + hi * 8];

  f32x4 o[4] = {};
  float mr = -1e30f, lr = 0.f;
  const unsigned long long* mrow = mbits + (size_t)(b * Sc + q0 + lo) * (Sc / 64);

  // staging: 512 threads, thread t fills LDS row = t>>3 (0..63), col-block = t&7 (linear
  // dest, required by global_load_lds); source col pre-swizzled (m201 both-sides pattern)
  const int srow = t >> 3, scb = t & 7;
  const int ksrc = ((scb ^ (srow & 7)) * 8);

  auto stage = [&](int buf, int kb) {
    async16(&Ks[buf][t * 8], Kp + (size_t)(kb + srow) * 64 + ksrc);
    async16(&Vs[buf][t * 8], Vp + (size_t)srow * Sc + kb + ksrc);
  };

  stage(0, 0);
  int cur = 0;
  const int xr = (lo & 7) << 3;               // elem-space XOR for swizzled reads

  for (int kb = 0; kb < Sc; kb += 64) {
    __syncthreads();   // vmcnt(0) drain: own staged loads landed; all waves done with
                       // the buffer about to be re-staged
    if (kb + 64 < Sc) stage(cur ^ 1, kb + 64);   // prefetch next tile under this iter's compute

    // ---- S^T tile: 64 keys x 16 q from staged K
    f32x4 sc[4];
    __builtin_amdgcn_s_setprio(1);
#pragma unroll
    for (int kc = 0; kc < 4; ++kc) {
      bf16x8 kf0 = *(const bf16x8*)&Ks[cur][(kc * 16 + lo) * 64 + ((hi * 8) ^ xr)];
      bf16x8 kf1 = *(const bf16x8*)&Ks[cur][(kc * 16 + lo) * 64 + ((32 + hi * 8) ^ xr)];
      f32x4 z = {0.f, 0.f, 0.f, 0.f};
      sc[kc] = __builtin_amdgcn_mfma_f32_16x16x32_bf16(kf0, qf[0], z, 0, 0, 0);
      sc[kc] = __builtin_amdgcn_mfma_f32_16x16x32_bf16(kf1, qf[1], sc[kc], 0, 0, 0);
    }
    __builtin_amdgcn_s_setprio(0);

    const unsigned long long mb = mrow[kb >> 6];
    if (!__all(mb == ~0ull)) {
#pragma unroll
      for (int kc = 0; kc < 4; ++kc)
#pragma unroll
        for (int r = 0; r < 4; ++r)
          if (!((mb >> (kc * 16 + hi * 4 + r)) & 1ull)) sc[kc][r] = -1e-9f;
    }
    float pmax = -1e30f;
#pragma unroll
    for (int kc = 0; kc < 4; ++kc)
#pragma unroll
      for (int r = 0; r < 4; ++r) pmax = fmaxf(pmax, sc[kc][r]);
    pmax = fmaxf(pmax, __shfl_xor(pmax, 16));
    pmax = fmaxf(pmax, __shfl_xor(pmax, 32));

    if (!__all(pmax <= mr + 8.f)) {           // T13 defer-max
      const float mn = fmaxf(mr, pmax);
      const float fs = exp2f((mr - mn) * LOG2E);
      lr *= fs;
#pragma unroll
      for (int d0 = 0; d0 < 4; ++d0) o[d0] *= fs;
      mr = mn;
    }
    const float mj = mr * LOG2E;
    float rs = 0.f;
#pragma unroll
    for (int kc = 0; kc < 4; ++kc)
#pragma unroll
      for (int r = 0; r < 4; ++r) {
        const float p = exp2f(__builtin_fmaf(sc[kc][r], LOG2E, -mj));
        sc[kc][r] = p; rs += p;
      }
    rs += __shfl_xor(rs, 16);
    rs += __shfl_xor(rs, 32);
    lr += rs;

#pragma unroll
    for (int kc = 0; kc < 4; ++kc) {          // P[q][k] -> LDS, 4x ds_write_b64
      bf16x4 pk;
#pragma unroll
      for (int r = 0; r < 4; ++r) pk[r] = (__bf16)sc[kc][r];
      *(bf16x4*)&Pq[wv][lo][kc * 16 + hi * 4] = pk;
    }
    bf16x8 pa0 = *(const bf16x8*)&Pq[wv][lo][hi * 8];
    bf16x8 pa1 = *(const bf16x8*)&Pq[wv][lo][32 + hi * 8];

    // ---- O += P V from staged V^T
    __builtin_amdgcn_s_setprio(1);
#pragma unroll
    for (int d0 = 0; d0 < 4; ++d0) {
      bf16x8 vf0 = *(const bf16x8*)&Vs[cur][(d0 * 16 + lo) * 64 + ((hi * 8) ^ xr)];
      bf16x8 vf1 = *(const bf16x8*)&Vs[cur][(d0 * 16 + lo) * 64 + ((32 + hi * 8) ^ xr)];
      o[d0] = __builtin_amdgcn_mfma_f32_16x16x32_bf16(vf0, pa0, o[d0], 0, 0, 0);
      o[d0] = __builtin_amdgcn_mfma_f32_16x16x32_bf16(vf1, pa1, o[d0], 0, 0, 0);
    }
    __builtin_amdgcn_s_setprio(0);
    cur ^= 1;
  }

  const float inv = 1.f / lr;
#pragma unroll
  for (int d0 = 0; d0 < 4; ++d0) {
    bf16x4 st;
#pragma unroll
    for (int r = 0; r < 4; ++r) st[r] = (__bf16)(o[d0][r] * inv);
    *(bf16x4*)&X[(size_t)(b * Sc + q0 + lo) * 1024 + h * 64 + d0 * 16 + hi * 4] = st;
  }
}

// ---------------------------------------------------------------- launcher
extern "C" void kernel_launch(void* const* d_in, const int* in_sizes, int n_in,
                              void* d_out, int out_size, void* d_ws, size_t ws_size,
                              hipStream_t stream) {
  const float* q  = (const float*)d_in[0];
  const float* k  = (const float*)d_in[1];
  const float* v  = (const float*)d_in[2];
  const int*   mask = (const int*)d_in[3];
  const float* Wq = (const float*)d_in[4];
  const float* bq = (const float*)d_in[5];
  const float* Wk = (const float*)d_in[6];
  const float* bk = (const float*)d_in[7];
  const float* Wv = (const float*)d_in[8];
  const float* bv = (const float*)d_in[9];
  const float* Wo = (const float*)d_in[10];
  const float* bo = (const float*)d_in[11];

  const size_t MB = 1u << 20;
  if (ws_size < 66 * MB) return;

  char* ws = (char*)d_ws;
  __bf16* wqb  = (__bf16*)(ws + 0 * MB);
  __bf16* wkb  = (__bf16*)(ws + 2 * MB);
  __bf16* wvb  = (__bf16*)(ws + 4 * MB);
  __bf16* wob  = (__bf16*)(ws + 6 * MB);
  __bf16* qbin = (__bf16*)(ws + 8 * MB);
  __bf16* kbin = (__bf16*)(ws + 16 * MB);
  __bf16* vbin = (__bf16*)(ws + 24 * MB);
  __bf16* Qh   = (__bf16*)(ws + 32 * MB);
  __bf16* Kh   = (__bf16*)(ws + 40 * MB);
  __bf16* Vt   = (__bf16*)(ws + 48 * MB);
  __bf16* Xat  = (__bf16*)(ws + 56 * MB);
  unsigned long long* mbits = (unsigned long long*)(ws + 64 * MB);

  const int nIn8 = Mrows * Dm / 8;   // 524288
  const int nW8  = Dm * Dm / 8;      // 131072
  cvt3<<<nIn8 / 256, 256, 0, stream>>>(q, k, v, qbin, kbin, vbin, nIn8);
  cvt4<<<nW8 / 256, 256, 0, stream>>>(Wq, Wk, Wv, Wo, wqb, wkb, wvb, wob, nW8);
  pack_mask<<<4096, 256, 0, stream>>>(mask, mbits);

  gemm_qkv<<<768, 256, 0, stream>>>(qbin, kbin, vbin, wqb, wkb, wvb, bq, bk, bv, Qh, Kh, Vt);

  attn_fwd<<<512, 512, 0, stream>>>(Qh, Kh, Vt, mbits, Xat);

  gemm_o<<<256, 256, 0, stream>>>(Xat, wob, bo, (float*)d_out);
}